// Round 1
// 1397.964 us; speedup vs baseline: 1.1343x; 1.1343x over previous
//
#include <hip/hip_runtime.h>
#include <cfloat>
#include <climits>
#include <math.h>

// Problem constants (fixed by setup_inputs)
#define N_CAND 200000
#define DTXT 768
#define DIMG 1024
#define DC 256
#define KTOP 10
#define NKV 11            // K+1 attention tokens
#define CHUNK 2000        // sims per top-k partial block
#define NBLK_TOPK 100     // N_CAND / CHUNK

__device__ __forceinline__ float wave_sum(float v) {
#pragma unroll
  for (int off = 32; off; off >>= 1) v += __shfl_xor(v, off, 64);
  return v;
}

// ---------------------------------------------------------------------------
// K1: sims[r] = dot(cand_text[r], q) / max(||cand_text[r]||, 1e-12)
// (same ordering as cosine sim; dividing by ||q|| is a positive constant)
// One wave per row; lane reads 3 float4 (64 lanes * 3 * 16B = 3 KB row).
// ---------------------------------------------------------------------------
__global__ void k_sims(const float* __restrict__ q, const float* __restrict__ ct,
                       float* __restrict__ sims) {
  const int lane = threadIdx.x & 63;
  const int wave = threadIdx.x >> 6;
  const int row = blockIdx.x * 4 + wave;
  if (row >= N_CAND) return;
  const float4* r4 = (const float4*)(ct + (size_t)row * DTXT);
  const float4* q4 = (const float4*)q;
  float dot = 0.f, nrm = 0.f;
#pragma unroll
  for (int i = 0; i < 3; ++i) {
    float4 a = r4[lane + i * 64];
    float4 b = q4[lane + i * 64];
    dot += a.x * b.x + a.y * b.y + a.z * b.z + a.w * b.w;
    nrm += a.x * a.x + a.y * a.y + a.z * a.z + a.w * a.w;
  }
  dot = wave_sum(dot);
  nrm = wave_sum(nrm);
  if (lane == 0) sims[row] = dot / fmaxf(sqrtf(nrm), 1e-12f);
}

// ---------------------------------------------------------------------------
// Block-wide argmax over LDS (val, idx) arrays; tie -> smaller original index
// (matches jax.lax.top_k first-occurrence). blockDim.x must be 256.
// Returns winning POSITION in sv/si to all threads.
// ---------------------------------------------------------------------------
__device__ int block_argmax_pos(float* sv, const int* si, int M) {
  const int t = threadIdx.x;
  __shared__ float wv[4];
  __shared__ int wp[4];
  float bv = -FLT_MAX;
  int bp = -1;
  for (int j = t; j < M; j += 256) {
    float v = sv[j];
    if (bp < 0 || v > bv || (v == bv && si[j] < si[bp])) { bv = v; bp = j; }
  }
#pragma unroll
  for (int off = 32; off; off >>= 1) {
    float ov = __shfl_xor(bv, off, 64);
    int op = __shfl_xor(bp, off, 64);
    if (op >= 0 && (bp < 0 || ov > bv || (ov == bv && si[op] < si[bp]))) {
      bv = ov; bp = op;
    }
  }
  if ((t & 63) == 0) { wv[t >> 6] = bv; wp[t >> 6] = bp; }
  __syncthreads();
  if (t == 0) {
#pragma unroll
    for (int w = 1; w < 4; ++w) {
      if (wp[w] >= 0 && (wp[0] < 0 || wv[w] > wv[0] ||
                         (wv[w] == wv[0] && si[wp[w]] < si[wp[0]]))) {
        wv[0] = wv[w]; wp[0] = wp[w];
      }
    }
  }
  __syncthreads();
  int res = wp[0];
  __syncthreads();   // all threads read wp[0] before next round's writes
  return res;
}

// ---------------------------------------------------------------------------
// K2a: per-block top-10 over a 2000-element chunk of sims
// ---------------------------------------------------------------------------
__global__ void k_topk_part(const float* __restrict__ sims,
                            float* __restrict__ cvals, int* __restrict__ cidx) {
  __shared__ float sv[CHUNK];
  __shared__ int si[CHUNK];
  const int t = threadIdx.x;
  const int lo = blockIdx.x * CHUNK;
  for (int j = t; j < CHUNK; j += 256) { sv[j] = sims[lo + j]; si[j] = lo + j; }
  __syncthreads();
  for (int r = 0; r < KTOP; ++r) {
    int p = block_argmax_pos(sv, si, CHUNK);
    if (t == 0) {
      cvals[blockIdx.x * KTOP + r] = sv[p];
      cidx[blockIdx.x * KTOP + r] = si[p];
      sv[p] = -INFINITY;
    }
    __syncthreads();
  }
}

// ---------------------------------------------------------------------------
// K2b: merge 100*10 candidates -> final 10 indices
// ---------------------------------------------------------------------------
__global__ void k_topk_final(const float* __restrict__ cvals,
                             const int* __restrict__ cidx,
                             int* __restrict__ fidx) {
  __shared__ float sv[NBLK_TOPK * KTOP];
  __shared__ int si[NBLK_TOPK * KTOP];
  const int t = threadIdx.x;
  for (int j = t; j < NBLK_TOPK * KTOP; j += 256) { sv[j] = cvals[j]; si[j] = cidx[j]; }
  __syncthreads();
  for (int r = 0; r < KTOP; ++r) {
    int p = block_argmax_pos(sv, si, NBLK_TOPK * KTOP);
    if (t == 0) { fidx[r] = si[p]; sv[p] = -INFINITY; }
    __syncthreads();
  }
}

// ---------------------------------------------------------------------------
// K3: the 21 projection rows: relu(LN(x @ W.T + b) * g + be)
//   block 0      : x = query            (txt weights) -> avail_feat
//   blocks 1..10 : x = cand_text[idx]   (txt weights) -> avail_nb
//   blocks 11..20: x = cand_img[idx]    (img weights) -> miss_nb
// 256 threads; thread t owns output element t (W row t, contiguous float4).
// ---------------------------------------------------------------------------
__global__ void k_proj(const float* __restrict__ q, const float* __restrict__ ct,
                       const float* __restrict__ ci,
                       const float* __restrict__ Wt, const float* __restrict__ bt,
                       const float* __restrict__ gt, const float* __restrict__ bet,
                       const float* __restrict__ Wi, const float* __restrict__ bi,
                       const float* __restrict__ gi, const float* __restrict__ bei,
                       const int* __restrict__ fidx,
                       float* __restrict__ af, float* __restrict__ anb,
                       float* __restrict__ mnb) {
  __shared__ float x[DIMG];
  __shared__ float tmp[DC];
  __shared__ float redm, redr;
  const int t = threadIdx.x;
  const int j = blockIdx.x;
  const float *W, *b, *g, *be, *src;
  float* dst;
  int D;
  if (j == 0) {
    src = q; D = DTXT; W = Wt; b = bt; g = gt; be = bet; dst = af;
  } else if (j < 11) {
    src = ct + (size_t)fidx[j - 1] * DTXT;
    D = DTXT; W = Wt; b = bt; g = gt; be = bet; dst = anb + (j - 1) * DC;
  } else {
    src = ci + (size_t)fidx[j - 11] * DIMG;
    D = DIMG; W = Wi; b = bi; g = gi; be = bei; dst = mnb + (j - 11) * DC;
  }
  for (int d = t; d < D; d += 256) x[d] = src[d];
  __syncthreads();
  const float4* w4 = (const float4*)(W + (size_t)t * D);
  float acc = 0.f;
  for (int d4 = 0; d4 < (D >> 2); ++d4) {
    float4 w = w4[d4];
    acc += w.x * x[4 * d4] + w.y * x[4 * d4 + 1] + w.z * x[4 * d4 + 2] +
           w.w * x[4 * d4 + 3];
  }
  acc += b[t];
  tmp[t] = acc;
  __syncthreads();
  if (t < 64) {
    float s = tmp[t] + tmp[t + 64] + tmp[t + 128] + tmp[t + 192];
    s = wave_sum(s);
    if (t == 0) redm = s * (1.f / 256.f);
  }
  __syncthreads();
  if (t < 64) {
    float s = 0.f;
#pragma unroll
    for (int kk = 0; kk < 4; ++kk) {
      float d0 = tmp[t + 64 * kk] - redm;
      s += d0 * d0;
    }
    s = wave_sum(s);
    if (t == 0) redr = rsqrtf(s * (1.f / 256.f) + 1e-5f);
  }
  __syncthreads();
  float y = (acc - redm) * redr * g[t] + be[t];
  dst[t] = fmaxf(y, 0.f);
}

// ---------------------------------------------------------------------------
// K4a: qp/kp/vp projections, parallelized across 23 blocks (was 1 block = 1 CU
// serially pulling Wq+Wk+Wv = 768 KB from HBM).
//   block 0      : qp  = af  @ Wq.T + bq
//   blocks 1..11 : kp[n] = K_n @ Wk.T + bk,  K_n = proto | anb[n-1]
//   blocks 12..22: vp[n] = V_n @ Wv.T + bv,  V_n = proto | mnb[n-1]
// Accumulation order identical to the previous fused kernel (bit-exact).
// ---------------------------------------------------------------------------
__global__ void k_qkv(const float* __restrict__ proto,
                      const float* __restrict__ Wq, const float* __restrict__ bq,
                      const float* __restrict__ Wk, const float* __restrict__ bk,
                      const float* __restrict__ Wv, const float* __restrict__ bv,
                      const float* __restrict__ af, const float* __restrict__ anb,
                      const float* __restrict__ mnb,
                      float* __restrict__ qp, float* __restrict__ kp,
                      float* __restrict__ vp) {
  __shared__ float x[DC];
  const int t = threadIdx.x;
  const int j = blockIdx.x;
  const float *W, *b, *src;
  float* dst;
  if (j == 0) {
    W = Wq; b = bq; src = af; dst = qp;
  } else if (j < 12) {
    const int n = j - 1;
    W = Wk; b = bk; src = (n == 0) ? proto : anb + (n - 1) * DC;
    dst = kp + n * DC;
  } else {
    const int n = j - 12;
    W = Wv; b = bv; src = (n == 0) ? proto : mnb + (n - 1) * DC;
    dst = vp + n * DC;
  }
  x[t] = src[t];
  __syncthreads();
  const float4* w4 = (const float4*)(W + (size_t)t * DC);
  float a = 0.f;
  for (int d4 = 0; d4 < DC / 4; ++d4) {
    float4 w = w4[d4];
    a += w.x * x[4 * d4] + w.y * x[4 * d4 + 1] + w.z * x[4 * d4 + 2] +
         w.w * x[4 * d4 + 3];
  }
  dst[t] = a + b[t];
}

// ---------------------------------------------------------------------------
// K4b: scores + softmax + ctx (tiny, latency-bound; 1 block)
// ---------------------------------------------------------------------------
__global__ void k_score_ctx(const float* __restrict__ qp,
                            const float* __restrict__ kp,
                            const float* __restrict__ vp,
                            float* __restrict__ ctx) {
  __shared__ float s_qp[DC];
  __shared__ float s_kp[NKV * DC];
  __shared__ float s_vp[NKV * DC];
  __shared__ float s_sc[4][NKV];
  __shared__ float s_at[4][NKV];
  const int t = threadIdx.x;
  s_qp[t] = qp[t];
  for (int i = t; i < NKV * DC; i += 256) { s_kp[i] = kp[i]; s_vp[i] = vp[i]; }
  __syncthreads();
  if (t < 4 * NKV) {
    int h = t / NKV, n = t % NKV;
    const float* qh = s_qp + h * 64;
    const float* kh = s_kp + n * DC + h * 64;
    float a = 0.f;
#pragma unroll
    for (int d = 0; d < 64; ++d) a += qh[d] * kh[d];
    s_sc[h][n] = a * 0.125f;
  }
  __syncthreads();
  if (t < 4) {
    float m = -INFINITY;
    for (int n = 0; n < NKV; ++n) m = fmaxf(m, s_sc[t][n]);
    float s = 0.f;
    for (int n = 0; n < NKV; ++n) {
      float e = expf(s_sc[t][n] - m);
      s_at[t][n] = e;
      s += e;
    }
    float inv = 1.f / s;
    for (int n = 0; n < NKV; ++n) s_at[t][n] *= inv;
  }
  __syncthreads();
  {
    int h = t >> 6;
    float a = 0.f;
#pragma unroll
    for (int n = 0; n < NKV; ++n) a += s_at[h][n] * s_vp[n * DC + t];
    ctx[t] = a;
  }
}

// ---------------------------------------------------------------------------
// K4c: attn_out = ctx @ Wo.T + bo + proto  (4 blocks x 64 outputs)
// ---------------------------------------------------------------------------
__global__ void k_wo(const float* __restrict__ Wo, const float* __restrict__ bo,
                     const float* __restrict__ proto,
                     const float* __restrict__ ctx, float* __restrict__ t1) {
  __shared__ float s_c[DC];
  const int t = threadIdx.x;  // 64
  ((float4*)s_c)[t] = ((const float4*)ctx)[t];
  __syncthreads();
  const int c = blockIdx.x * 64 + t;
  const float4* w4 = (const float4*)(Wo + (size_t)c * DC);
  float a = 0.f;
  for (int d4 = 0; d4 < DC / 4; ++d4) {
    float4 w = w4[d4];
    a += w.x * s_c[4 * d4] + w.y * s_c[4 * d4 + 1] + w.z * s_c[4 * d4 + 2] +
         w.w * s_c[4 * d4 + 3];
  }
  t1[c] = a + bo[c] + proto[c];
}

// ---------------------------------------------------------------------------
// K4d: LN1 (recomputed redundantly per block from the 1 KB vector, identical
// reduction tree -> bit-exact) + FFN layer 1.  8 blocks x 128 outputs.
// Block 0 also persists o1 for K4e/K4f.
// ---------------------------------------------------------------------------
__global__ void k_ffn1(const float* __restrict__ g1, const float* __restrict__ be1,
                       const float* __restrict__ W1, const float* __restrict__ b1,
                       const float* __restrict__ t1, float* __restrict__ o1w,
                       float* __restrict__ h) {
  __shared__ float s_t[DC];
  __shared__ float s_o1[DC];
  __shared__ float redm, redr;
  const int t = threadIdx.x;  // 256
  s_t[t] = t1[t];
  __syncthreads();
  if (t < 64) {
    float s = s_t[t] + s_t[t + 64] + s_t[t + 128] + s_t[t + 192];
    s = wave_sum(s);
    if (t == 0) redm = s * (1.f / 256.f);
  }
  __syncthreads();
  if (t < 64) {
    float s = 0.f;
#pragma unroll
    for (int kk = 0; kk < 4; ++kk) {
      float d0 = s_t[t + 64 * kk] - redm;
      s += d0 * d0;
    }
    s = wave_sum(s);
    if (t == 0) redr = rsqrtf(s * (1.f / 256.f) + 1e-5f);
  }
  __syncthreads();
  s_o1[t] = (s_t[t] - redm) * redr * g1[t] + be1[t];
  __syncthreads();
  if (blockIdx.x == 0) o1w[t] = s_o1[t];
  if (t < 128) {
    const int o = blockIdx.x * 128 + t;
    const float4* w4 = (const float4*)(W1 + (size_t)o * DC);
    float a = 0.f;
    for (int d4 = 0; d4 < DC / 4; ++d4) {
      float4 w = w4[d4];
      a += w.x * s_o1[4 * d4] + w.y * s_o1[4 * d4 + 1] +
           w.z * s_o1[4 * d4 + 2] + w.w * s_o1[4 * d4 + 3];
    }
    h[o] = fmaxf(a + b1[o], 0.f);
  }
}

// ---------------------------------------------------------------------------
// K4e: FFN layer 2 + residual.  4 blocks x 64 outputs.
// ---------------------------------------------------------------------------
__global__ void k_ffn2(const float* __restrict__ W2, const float* __restrict__ b2,
                       const float* __restrict__ o1w, const float* __restrict__ h,
                       float* __restrict__ t2) {
  __shared__ float s_h[4 * DC];
  const int t = threadIdx.x;  // 64
#pragma unroll
  for (int i = 0; i < 4; ++i)
    ((float4*)s_h)[t + 64 * i] = ((const float4*)h)[t + 64 * i];
  __syncthreads();
  const int c = blockIdx.x * 64 + t;
  const float4* w4 = (const float4*)(W2 + (size_t)c * 4 * DC);
  float a = 0.f;
  for (int d4 = 0; d4 < DC; ++d4) {  // 1024/4
    float4 w = w4[d4];
    a += w.x * s_h[4 * d4] + w.y * s_h[4 * d4 + 1] + w.z * s_h[4 * d4 + 2] +
         w.w * s_h[4 * d4 + 3];
  }
  t2[c] = a + b2[c] + o1w[c];
}

// ---------------------------------------------------------------------------
// K4f: LN2 + proto -> out  (tiny, 1 block; identical reduction tree)
// ---------------------------------------------------------------------------
__global__ void k_ln2(const float* __restrict__ g2, const float* __restrict__ be2,
                      const float* __restrict__ proto,
                      const float* __restrict__ t2, float* __restrict__ out) {
  __shared__ float s_t[DC];
  __shared__ float redm, redr;
  const int t = threadIdx.x;  // 256
  s_t[t] = t2[t];
  __syncthreads();
  if (t < 64) {
    float s = s_t[t] + s_t[t + 64] + s_t[t + 128] + s_t[t + 192];
    s = wave_sum(s);
    if (t == 0) redm = s * (1.f / 256.f);
  }
  __syncthreads();
  if (t < 64) {
    float s = 0.f;
#pragma unroll
    for (int kk = 0; kk < 4; ++kk) {
      float d0 = s_t[t + 64 * kk] - redm;
      s += d0 * d0;
    }
    s = wave_sum(s);
    if (t == 0) redr = rsqrtf(s * (1.f / 256.f) + 1e-5f);
  }
  __syncthreads();
  out[t] = (s_t[t] - redm) * redr * g2[t] + be2[t] + proto[t];
}

// ---------------------------------------------------------------------------
extern "C" void kernel_launch(void* const* d_in, const int* in_sizes, int n_in,
                              void* d_out, int out_size, void* d_ws,
                              size_t ws_size, hipStream_t stream) {
  (void)in_sizes; (void)n_in; (void)out_size; (void)ws_size;
  const float* query = (const float*)d_in[0];
  const float* ct    = (const float*)d_in[1];
  const float* ci    = (const float*)d_in[2];
  const float* proto = (const float*)d_in[3];
  const float* Wt    = (const float*)d_in[4];
  const float* bt    = (const float*)d_in[5];
  const float* gt    = (const float*)d_in[6];
  const float* bet   = (const float*)d_in[7];
  const float* Wi    = (const float*)d_in[8];
  const float* bi    = (const float*)d_in[9];
  const float* gi    = (const float*)d_in[10];
  const float* bei   = (const float*)d_in[11];
  const float* Wq    = (const float*)d_in[12];
  const float* bq    = (const float*)d_in[13];
  const float* Wk    = (const float*)d_in[14];
  const float* bk    = (const float*)d_in[15];
  const float* Wv    = (const float*)d_in[16];
  const float* bv    = (const float*)d_in[17];
  const float* Wo    = (const float*)d_in[18];
  const float* bo    = (const float*)d_in[19];
  const float* g1    = (const float*)d_in[20];
  const float* be1   = (const float*)d_in[21];
  const float* W1    = (const float*)d_in[22];
  const float* b1    = (const float*)d_in[23];
  const float* W2    = (const float*)d_in[24];
  const float* b2    = (const float*)d_in[25];
  const float* g2    = (const float*)d_in[26];
  const float* be2   = (const float*)d_in[27];
  float* out = (float*)d_out;

  // Workspace layout (all 4B-aligned; total < 1 MB)
  char* ws = (char*)d_ws;
  float* sims  = (float*)(ws);            // 200000 floats
  float* cvals = (float*)(ws + 800000);   // 1000 floats
  int*   cidx  = (int*)(ws + 804000);     // 1000 ints
  int*   fidx  = (int*)(ws + 808000);     // 10 ints (pad to 808064)
  float* af    = (float*)(ws + 808064);   // 256
  float* anb   = (float*)(ws + 809088);   // 10*256
  float* mnb   = (float*)(ws + 819328);   // 10*256
  float* qp    = (float*)(ws + 829568);   // 256
  float* kp    = (float*)(ws + 830592);   // 11*256
  float* vp    = (float*)(ws + 841856);   // 11*256
  float* ctx   = (float*)(ws + 853120);   // 256
  float* t1    = (float*)(ws + 854144);   // 256
  float* o1w   = (float*)(ws + 855168);   // 256
  float* h     = (float*)(ws + 856192);   // 1024
  float* t2    = (float*)(ws + 860288);   // 256

  k_sims<<<dim3(N_CAND / 4), dim3(256), 0, stream>>>(query, ct, sims);
  k_topk_part<<<dim3(NBLK_TOPK), dim3(256), 0, stream>>>(sims, cvals, cidx);
  k_topk_final<<<dim3(1), dim3(256), 0, stream>>>(cvals, cidx, fidx);
  k_proj<<<dim3(21), dim3(256), 0, stream>>>(query, ct, ci, Wt, bt, gt, bet, Wi,
                                             bi, gi, bei, fidx, af, anb, mnb);
  k_qkv<<<dim3(23), dim3(256), 0, stream>>>(proto, Wq, bq, Wk, bk, Wv, bv, af,
                                            anb, mnb, qp, kp, vp);
  k_score_ctx<<<dim3(1), dim3(256), 0, stream>>>(qp, kp, vp, ctx);
  k_wo<<<dim3(4), dim3(64), 0, stream>>>(Wo, bo, proto, ctx, t1);
  k_ffn1<<<dim3(8), dim3(256), 0, stream>>>(g1, be1, W1, b1, t1, o1w, h);
  k_ffn2<<<dim3(4), dim3(64), 0, stream>>>(W2, b2, o1w, h, t2);
  k_ln2<<<dim3(1), dim3(256), 0, stream>>>(g2, be2, proto, t2, out);
}